// Round 5
// baseline (592.018 us; speedup 1.0000x reference)
//
#include <hip/hip_runtime.h>

// TriMul: B=2, S=256, DIM=128, HID=128
// R1-proven arithmetic (absmax 1.17e-2, bit-stable since R4). R11 =
// R9 (stage2/stage3/cvt reverted verbatim from the 267.9us version; the
// R10 fusion regressed 2x and is abandoned) + stage1 restructure:
//  - oS LDS tile ELIMINATED: epilogues store straight from registers to
//    global (operand-swapped OG, 8B packed stores; L2 assembles full
//    lines since each block writes all 64 j of every h-row).
//  - LDS 36KB -> 17.7KB => 8 blocks/CU, __launch_bounds__(256,8); all
//    2048 blocks co-resident (no wave ramp).
//  - 6 barriers -> 1 (only the LN->xnS barrier remains).
//  Values stored are the identical f2b'd shorts -> bit-identical output.
// Fixed ~85us per-iteration harness overhead identified (constant across
// R0-R4 fits); kernel-sum is the optimizable part.
// HARD RULE (R2/R3): never touch arithmetic statements, value-producing
// operand order semantics, reduction pairing, or sigmoid form. absmax
// must stay exactly 0.01171875.

#define SS 256
#define DD 128
#define HH 128

typedef __attribute__((ext_vector_type(8))) short bf16x8;
typedef __attribute__((ext_vector_type(4))) short bf16x4;
typedef __attribute__((ext_vector_type(4))) float f32x4;

__device__ __forceinline__ unsigned short f2b(float f) {
  unsigned u = __builtin_bit_cast(unsigned, f);
  u = (u + 0x7FFFu + ((u >> 16) & 1u)) >> 16;
  return (unsigned short)u;
}
__device__ __forceinline__ float b2f(unsigned short h) {
  return __builtin_bit_cast(float, ((unsigned)h) << 16);
}
__device__ __forceinline__ float sigmoidf_(float x) {
  return 1.0f / (1.0f + expf(-x));
}

// ---------------- stage 0: weight fp32 -> bf16 (x4 vectorized) ----------------
__global__ __launch_bounds__(1024) void k_cvt(
    const float* __restrict__ s0, const float* __restrict__ s1,
    const float* __restrict__ s2, const float* __restrict__ s3,
    const float* __restrict__ s4, const float* __restrict__ s5,
    unsigned short* __restrict__ dst)
{
  int m = blockIdx.x >> 2;
  int e4 = (((blockIdx.x & 3) << 10) | threadIdx.x) << 2;
  const float* s = (m == 0) ? s0 : (m == 1) ? s1 : (m == 2) ? s2
                 : (m == 3) ? s3 : (m == 4) ? s4 : s5;
  f32x4 v = *(const f32x4*)(s + e4);
  bf16x4 r;
  #pragma unroll
  for (int i = 0; i < 4; ++i) r[i] = (short)f2b(v[i]);
  *(bf16x4*)(dst + m * 16384 + e4) = r;
}

// ---------------- stage 1: LN + 5 projections + gates ----------------
__global__ __launch_bounds__(256, 8) void k_stage1(
    const float* __restrict__ x, const float* __restrict__ mask,
    const float* __restrict__ nw, const float* __restrict__ nb,
    const unsigned short* __restrict__ wb,   // [6][128][128] bf16: L,R,LG,RG,OG,O
    unsigned short* __restrict__ Lt, unsigned short* __restrict__ Rt,
    unsigned short* __restrict__ og)
{
  __shared__ unsigned short xnS[64][136];
  __shared__ float maskS[64];

  const int tid  = threadIdx.x;
  const int wave = tid >> 6, lane = tid & 63;
  const int quad = lane >> 4, l16 = lane & 15;
  const int r0 = blockIdx.x * 64;
  const int bq = r0 >> 16, iq = (r0 >> 8) & 255, j0 = r0 & 255;

  if (tid < 64) maskS[tid] = mask[r0 + tid];

  // ---- LayerNorm over D=128, 16 rows per wave (R1-proven bits) ----
  const float w0 = nw[lane], w1 = nw[lane + 64];
  const float b0 = nb[lane], b1 = nb[lane + 64];
  float v0a[16], v1a[16];
  #pragma unroll
  for (int rr = 0; rr < 16; ++rr) {
    const float* xr = x + (size_t)(r0 + wave * 16 + rr) * DD;
    v0a[rr] = xr[lane];
    v1a[rr] = xr[lane + 64];
  }
  #pragma unroll
  for (int rr = 0; rr < 16; ++rr) {
    int r = wave * 16 + rr;
    float v0 = v0a[rr], v1 = v1a[rr];
    float s = v0 + v1;
    #pragma unroll
    for (int o = 32; o; o >>= 1) s += __shfl_xor(s, o);
    float mu = s * (1.0f / 128.0f);
    float d0 = v0 - mu, d1 = v1 - mu;
    float q = d0 * d0 + d1 * d1;
    #pragma unroll
    for (int o = 32; o; o >>= 1) q += __shfl_xor(q, o);
    float rs = rsqrtf(q * (1.0f / 128.0f) + 1e-5f);
    xnS[r][lane]      = f2b(d0 * rs * w0 + b0);
    xnS[r][lane + 64] = f2b(d1 * rs * w1 + b1);
  }
  __syncthreads();   // sole barrier

  const int h0 = wave * 32;      // this wave's h-slice (2 x 16)
  const int jl = quad * 4;       // j offset within a 16-row tile (+rg)

  // gated compute: value & gate projections interleaved over kk, this
  // wave's 32-h slice, all 64 rows. Per-acc MFMA order identical to R7-R9.
  auto gatedCompute = [&](const unsigned short* __restrict__ Wv,
                          const unsigned short* __restrict__ Wg,
                          f32x4 (&aV)[4][2], f32x4 (&aG)[4][2]) {
    const unsigned short* pv = Wv + (h0 + l16) * 128 + quad * 8;
    const unsigned short* pg = Wg + (h0 + l16) * 128 + quad * 8;
    #pragma unroll
    for (int rt = 0; rt < 4; ++rt)
      #pragma unroll
      for (int n = 0; n < 2; ++n) {
        aV[rt][n] = f32x4{0.f, 0.f, 0.f, 0.f};
        aG[rt][n] = f32x4{0.f, 0.f, 0.f, 0.f};
      }
    bf16x8 bv[2], bg[2], bvn[2], bgn[2];
    #pragma unroll
    for (int n = 0; n < 2; ++n) {
      bv[n] = *(const bf16x8*)(pv + n * 2048);
      bg[n] = *(const bf16x8*)(pg + n * 2048);
    }
    #pragma unroll
    for (int kk = 0; kk < 4; ++kk) {
      if (kk < 3) {
        #pragma unroll
        for (int n = 0; n < 2; ++n) {
          bvn[n] = *(const bf16x8*)(pv + n * 2048 + (kk + 1) * 32);
          bgn[n] = *(const bf16x8*)(pg + n * 2048 + (kk + 1) * 32);
        }
      }
      #pragma unroll
      for (int rt = 0; rt < 4; ++rt) {
        bf16x8 a = *(const bf16x8*)&xnS[rt * 16 + l16][kk * 32 + quad * 8];
        #pragma unroll
        for (int n = 0; n < 2; ++n) {
          aG[rt][n] = __builtin_amdgcn_mfma_f32_16x16x32_bf16(a, bg[n], aG[rt][n], 0, 0, 0);
          aV[rt][n] = __builtin_amdgcn_mfma_f32_16x16x32_bf16(a, bv[n], aV[rt][n], 0, 0, 0);
        }
      }
      #pragma unroll
      for (int n = 0; n < 2; ++n) { bv[n] = bvn[n]; bg[n] = bgn[n]; }
    }
  };

  // gated epilogue: same formulas, direct packed 8B stores to global.
  // Layout Lt/Rt[b][h][i=iq][j]: lane owns j = rt*16+jl..+3 (contiguous)
  // at row h = h0+n*16+l16. L2 assembles full lines (block covers all j).
  auto gatedStore = [&](f32x4 (&aV)[4][2], f32x4 (&aG)[4][2],
                        unsigned short* __restrict__ dstBase) {
    #pragma unroll
    for (int rt = 0; rt < 4; ++rt)
      #pragma unroll
      for (int n = 0; n < 2; ++n) {
        bf16x4 p;
        #pragma unroll
        for (int rg = 0; rg < 4; ++rg) {
          float g = sigmoidf_(aG[rt][n][rg]);
          p[rg] = (short)f2b(aV[rt][n][rg] * maskS[rt * 16 + jl + rg] * g);
        }
        *(bf16x4*)(dstBase +
            (((size_t)bq * 128 + h0 + n * 16 + l16) * 256 + iq) * 256 +
            j0 + rt * 16 + jl) = p;
      }
  };

  f32x4 aV[4][2], aG[4][2];

  // ---- LEFT ----
  gatedCompute(wb + 0 * 16384, wb + 2 * 16384, aV, aG);
  gatedStore(aV, aG, Lt);
  // ---- RIGHT ----
  gatedCompute(wb + 1 * 16384, wb + 3 * 16384, aV, aG);
  gatedStore(aV, aG, Rt);

  // ---- OUT GATE (operand-swapped: lane owns 4 consecutive h at j=l16) ----
  {
    const unsigned short* po = wb + 4 * 16384 + (h0 + l16) * 128 + quad * 8;
    f32x4 aO[4][2];
    #pragma unroll
    for (int rt = 0; rt < 4; ++rt)
      #pragma unroll
      for (int n = 0; n < 2; ++n) aO[rt][n] = f32x4{0.f, 0.f, 0.f, 0.f};
    bf16x8 bo[2], bon[2];
    #pragma unroll
    for (int n = 0; n < 2; ++n) bo[n] = *(const bf16x8*)(po + n * 2048);
    #pragma unroll
    for (int kk = 0; kk < 4; ++kk) {
      if (kk < 3) {
        #pragma unroll
        for (int n = 0; n < 2; ++n)
          bon[n] = *(const bf16x8*)(po + n * 2048 + (kk + 1) * 32);
      }
      #pragma unroll
      for (int rt = 0; rt < 4; ++rt) {
        bf16x8 a = *(const bf16x8*)&xnS[rt * 16 + l16][kk * 32 + quad * 8];
        #pragma unroll
        for (int n = 0; n < 2; ++n)
          aO[rt][n] = __builtin_amdgcn_mfma_f32_16x16x32_bf16(bo[n], a, aO[rt][n], 0, 0, 0);
      }
      #pragma unroll
      for (int n = 0; n < 2; ++n) bo[n] = bon[n];
    }
    // direct store: og[(r0 + j)*128 + h], j = rt*16+l16, h = h0+n*16+quad*4..+3
    #pragma unroll
    for (int rt = 0; rt < 4; ++rt)
      #pragma unroll
      for (int n = 0; n < 2; ++n) {
        bf16x4 p;
        #pragma unroll
        for (int rg = 0; rg < 4; ++rg)
          p[rg] = (short)f2b(sigmoidf_(aO[rt][n][rg]));
        *(bf16x4*)(og + (size_t)(r0 + rt * 16 + l16) * HH +
                   h0 + n * 16 + quad * 4) = p;
      }
  }
}

// ---------------- stage 2: batched 256x256x256 A.B^T per (b,h) ----------------
__global__ __launch_bounds__(256, 4) void k_stage2(
    const unsigned short* __restrict__ Lt, const unsigned short* __restrict__ Rt,
    unsigned short* __restrict__ Tt)
{
  __shared__ unsigned short As[128][72];
  __shared__ unsigned short Bs[128][72];

  const int tid  = threadIdx.x;
  const int wave = tid >> 6, lane = tid & 63;
  const int quad = lane >> 4, l16 = lane & 15;

  // XCD-pairing swizzle (R8): jt=0/1 pair of one (bh,it) share an XCD L2.
  const int w   = blockIdx.y * 4 + blockIdx.x;
  const int grp = w >> 4;
  const int xcd = w & 7;
  const int jt  = (w >> 3) & 1;
  const int pid = grp * 8 + xcd;      // [0,512)
  const int bh  = pid >> 1;
  const int it  = pid & 1;

  const unsigned short* A  = Lt + (size_t)bh * 65536 + it * 128 * 256;
  const unsigned short* Bp = Rt + (size_t)bh * 65536 + jt * 128 * 256;

  f32x4 acc[2][8];
  #pragma unroll
  for (int mt = 0; mt < 2; ++mt)
    #pragma unroll
    for (int nt = 0; nt < 8; ++nt) acc[mt][nt] = f32x4{0.f, 0.f, 0.f, 0.f};

  const int srow = tid >> 3, sc8 = tid & 7;

  // reg-staged pipeline: chunk ks lives in ra/rb while chunk ks-1 computes
  bf16x8 ra[4], rb[4];
  #pragma unroll
  for (int i = 0; i < 4; ++i) {
    ra[i] = *(const bf16x8*)(A  + (i * 32 + srow) * 256 + sc8 * 8);
    rb[i] = *(const bf16x8*)(Bp + (i * 32 + srow) * 256 + sc8 * 8);
  }

  #pragma unroll
  for (int ks = 0; ks < 4; ++ks) {
    #pragma unroll
    for (int i = 0; i < 4; ++i) {
      *(bf16x8*)&As[i * 32 + srow][sc8 * 8] = ra[i];
      *(bf16x8*)&Bs[i * 32 + srow][sc8 * 8] = rb[i];
    }
    __syncthreads();
    if (ks < 3) {   // issue next chunk now; latency hides under MFMA below
      #pragma unroll
      for (int i = 0; i < 4; ++i) {
        ra[i] = *(const bf16x8*)(A  + (i * 32 + srow) * 256 + (ks + 1) * 64 + sc8 * 8);
        rb[i] = *(const bf16x8*)(Bp + (i * 32 + srow) * 256 + (ks + 1) * 64 + sc8 * 8);
      }
    }
    // operand-swapped: first op = Rt frag (j), second = Lt frag (i).
    // Same products, same k-order -> same bits, C transposed:
    // j <- wave*32+mt*16+quad*4+rg, i <- nt*16+l16.
    #pragma unroll
    for (int k2 = 0; k2 < 2; ++k2) {
      int ko = k2 * 32 + quad * 8;
      bf16x8 r0f = *(const bf16x8*)&Bs[wave * 32 + l16][ko];
      bf16x8 r1f = *(const bf16x8*)&Bs[wave * 32 + 16 + l16][ko];
      #pragma unroll
      for (int nt = 0; nt < 8; ++nt) {
        bf16x8 lf = *(const bf16x8*)&As[nt * 16 + l16][ko];
        acc[0][nt] = __builtin_amdgcn_mfma_f32_16x16x32_bf16(r0f, lf, acc[0][nt], 0, 0, 0);
        acc[1][nt] = __builtin_amdgcn_mfma_f32_16x16x32_bf16(r1f, lf, acc[1][nt], 0, 0, 0);
      }
    }
    __syncthreads();
  }

  // packed 8B stores: lane owns 4 consecutive j at row i = nt*16+l16
  unsigned short* C = Tt + (size_t)bh * 65536 + it * 128 * 256 + jt * 128;
  #pragma unroll
  for (int mt = 0; mt < 2; ++mt)
    #pragma unroll
    for (int nt = 0; nt < 8; ++nt) {
      bf16x4 p;
      #pragma unroll
      for (int rg = 0; rg < 4; ++rg) p[rg] = (short)f2b(acc[mt][nt][rg]);
      *(bf16x4*)&C[(nt * 16 + l16) * 256 + wave * 32 + mt * 16 + quad * 4] = p;
    }
}

// ---------------- stage 3: LN over h * gate, @ w_out^T ----------------
__global__ __launch_bounds__(256, 4) void k_stage3(
    const unsigned short* __restrict__ Tt, const unsigned short* __restrict__ og,
    const float* __restrict__ onw, const float* __restrict__ onb,
    const unsigned short* __restrict__ wbO, float* __restrict__ out)
{
  __shared__ unsigned short tS[128][72];    // [h][j-swizzled] tri tile
  __shared__ unsigned short vS[64][136];    // [j][h]
  __shared__ float onwS[128], onbS[128];

  const int tid  = threadIdx.x;
  const int wave = tid >> 6, lane = tid & 63;
  const int quad = lane >> 4, l16 = lane & 15;
  const int r0 = blockIdx.x * 64;
  const int bq = r0 >> 16, iq = (r0 >> 8) & 255, j0 = r0 & 255;
  const int jw = wave * 16;                 // this wave's private j rows

  // early og prefetch for this lane's elementwise slice (hidden latency)
  const int jE = jw + (lane >> 2), hq = lane & 3;
  bf16x8 gpre[4];
  {
    const unsigned short* ogp = og + (size_t)(r0 + jE) * HH + hq * 32;
    #pragma unroll
    for (int c = 0; c < 4; ++c) gpre[c] = *(const bf16x8*)(ogp + c * 8);
  }

  if (tid < 128) { onwS[tid] = onw[tid]; onbS[tid] = onb[tid]; }

  // load tri tile [128 h][64 j]; j-block (j>>3) XOR'd with (h>>5)&3 so the
  // transpose read's 4 row-groups hit different banks (pure addr permutation)
  {
    int h = tid >> 1, half = tid & 1;
    int g = (h >> 5) & 3;
    const bf16x8* s = (const bf16x8*)(Tt +
        ((((size_t)bq * 128 + h) * 256 + iq) * 256 + j0 + half * 32));
    #pragma unroll
    for (int c = 0; c < 4; ++c)
      *(bf16x8*)&tS[h][((half * 4 + c) ^ g) << 3] = s[c];
  }
  __syncthreads();   // sole block-wide barrier

  // ---- wave-private from here on: wave owns j in [jw, jw+16) ----
  // transpose tS[h][j] -> vS[j][h] for the wave's 16 j (bit moves only)
  {
    int j  = jw + (lane & 15);
    int g2 = (lane >> 4) & 3;                // == (row>>5)&3 for this lane
    int hb = (lane >> 4) * 32;
    int jc = (((j >> 3) ^ g2) << 3) | (j & 7);
    #pragma unroll
    for (int c = 0; c < 4; ++c) {
      bf16x8 t;
      #pragma unroll
      for (int e = 0; e < 8; ++e) t[e] = (short)tS[hb + c * 8 + e][jc];
      *(bf16x8*)&vS[j][hb + c * 8] = t;
    }
  }
  asm volatile("s_waitcnt lgkmcnt(0)" ::: "memory");

  // stats: identical h-order summation & shfl pairing as before.
  float mu, rs;
  {
    int j = jw + ((lane & 31) >> 1), h0 = (lane & 1) * 64;
    float s = 0.f, q = 0.f;
    #pragma unroll
    for (int c = 0; c < 8; ++c) {
      bf16x8 v8 = *(const bf16x8*)&vS[j][h0 + c * 8];
      #pragma unroll
      for (int e = 0; e < 8; ++e) {
        float v = b2f((unsigned short)v8[e]);
        s += v; q += v * v;
      }
    }
    s += __shfl_xor(s, 1);
    q += __shfl_xor(q, 1);
    mu = s * (1.0f / 128.0f);
    float var = q * (1.0f / 128.0f) - mu * mu;
    rs = rsqrtf(var + 1e-5f);
  }
  mu = __shfl(mu, (jE - jw) << 1);
  rs = __shfl(rs, (jE - jw) << 1);

  // elementwise normalize * gate (same formulas), wave-private rows
  {
    unsigned short* vp = &vS[jE][hq * 32];
    #pragma unroll
    for (int c = 0; c < 4; ++c) {
      bf16x8 tv = *(bf16x8*)&vp[c * 8];
      bf16x8 gv = gpre[c];
      bf16x8 r;
      #pragma unroll
      for (int e = 0; e < 8; ++e) {
        int hh = hq * 32 + c * 8 + e;
        float v = (b2f((unsigned short)tv[e]) - mu) * rs * onwS[hh] + onbS[hh];
        r[e] = (short)f2b(v * b2f((unsigned short)gv[e]));
      }
      *(bf16x8*)&vp[c * 8] = r;
    }
  }
  asm volatile("s_waitcnt lgkmcnt(0)" ::: "memory");

  // out[j][d] = vS[j][:] @ w_out^T  (wave's 16 rows)
  // operand-swapped: first op = w_out frag (d), second = vS frag (j).
  // d <- nt*16+quad*4+rg (4 consecutive -> dwordx4 store), j <- jw+l16.
  f32x4 acc[8];
  #pragma unroll
  for (int nt = 0; nt < 8; ++nt) acc[nt] = f32x4{0.f, 0.f, 0.f, 0.f};
  #pragma unroll
  for (int kk = 0; kk < 4; ++kk) {
    bf16x8 xv = *(const bf16x8*)&vS[jw + l16][kk * 32 + quad * 8];
    #pragma unroll
    for (int nt = 0; nt < 8; ++nt) {
      bf16x8 wv = *(const bf16x8*)(wbO + (nt * 16 + l16) * 128 + kk * 32 + quad * 8);
      acc[nt] = __builtin_amdgcn_mfma_f32_16x16x32_bf16(wv, xv, acc[nt], 0, 0, 0);
    }
  }
  #pragma unroll
  for (int nt = 0; nt < 8; ++nt)
    *(f32x4*)&out[(size_t)(r0 + jw + l16) * DD + nt * 16 + quad * 4] = acc[nt];
}

extern "C" void kernel_launch(void* const* d_in, const int* in_sizes, int n_in,
                              void* d_out, int out_size, void* d_ws, size_t ws_size,
                              hipStream_t stream)
{
  const float* x    = (const float*)d_in[0];
  const float* mask = (const float*)d_in[1];
  const float* nw   = (const float*)d_in[2];
  const float* nb   = (const float*)d_in[3];
  const float* wL   = (const float*)d_in[4];
  const float* wR   = (const float*)d_in[5];
  const float* wLG  = (const float*)d_in[6];
  const float* wRG  = (const float*)d_in[7];
  const float* wOG  = (const float*)d_in[8];
  const float* onw  = (const float*)d_in[9];
  const float* onb  = (const float*)d_in[10];
  const float* wO   = (const float*)d_in[11];

  char* ws = (char*)d_ws;
  unsigned short* wb = (unsigned short*)ws;
  unsigned short* og = (unsigned short*)(ws + (1 << 18));
  unsigned short* Lt = (unsigned short*)(ws + (1 << 18) + 1 * (size_t)(1 << 25));
  unsigned short* Rt = (unsigned short*)(ws + (1 << 18) + 2 * (size_t)(1 << 25));
  unsigned short* Tt = (unsigned short*)(ws + (1 << 18) + 3 * (size_t)(1 << 25));

  k_cvt<<<24, 1024, 0, stream>>>(wL, wR, wLG, wRG, wOG, wO, wb);
  k_stage1<<<2048, 256, 0, stream>>>(x, mask, nw, nb, wb, Lt, Rt, og);
  k_stage2<<<dim3(4, 256), 256, 0, stream>>>(Lt, Rt, Tt);
  k_stage3<<<2048, 256, 0, stream>>>(Tt, og, onw, onb, wb + 5 * 16384, (float*)d_out);
}

// Round 6
// 320.982 us; speedup vs baseline: 1.8444x; 1.8444x over previous
//
#include <hip/hip_runtime.h>

// TriMul: B=2, S=256, DIM=128, HID=128
// R1-proven arithmetic (absmax 1.17e-2, bit-stable since R4). R12 = R11
// with the occupancy bug fixed:
//  - R11's __launch_bounds__(256,8) capped VGPRs at 64 < ~100 needed ->
//    full accumulator spill to scratch (WRITE_SIZE 98MB -> 1.02GB, 4.6x
//    regression). RULE: min_waves x VGPR_need <= 512 before touching
//    launch bounds.
//  - stage1 keeps the R11 structure (no oS tile, direct packed stores,
//    single barrier, 17.9KB LDS) at __launch_bounds__(256,4): 128-VGPR
//    budget, zero spill, 4 blocks/CU (VGPR-pinned anyway).
//  - stage2/stage3/cvt: R9-proven versions, untouched.
// HARD RULE (R2/R3): never touch arithmetic statements, value-producing
// operand order semantics, reduction pairing, or sigmoid form. absmax
// must stay exactly 0.01171875.

#define SS 256
#define DD 128
#define HH 128

typedef __attribute__((ext_vector_type(8))) short bf16x8;
typedef __attribute__((ext_vector_type(4))) short bf16x4;
typedef __attribute__((ext_vector_type(4))) float f32x4;

__device__ __forceinline__ unsigned short f2b(float f) {
  unsigned u = __builtin_bit_cast(unsigned, f);
  u = (u + 0x7FFFu + ((u >> 16) & 1u)) >> 16;
  return (unsigned short)u;
}
__device__ __forceinline__ float b2f(unsigned short h) {
  return __builtin_bit_cast(float, ((unsigned)h) << 16);
}
__device__ __forceinline__ float sigmoidf_(float x) {
  return 1.0f / (1.0f + expf(-x));
}

// ---------------- stage 0: weight fp32 -> bf16 (x4 vectorized) ----------------
__global__ __launch_bounds__(1024) void k_cvt(
    const float* __restrict__ s0, const float* __restrict__ s1,
    const float* __restrict__ s2, const float* __restrict__ s3,
    const float* __restrict__ s4, const float* __restrict__ s5,
    unsigned short* __restrict__ dst)
{
  int m = blockIdx.x >> 2;
  int e4 = (((blockIdx.x & 3) << 10) | threadIdx.x) << 2;
  const float* s = (m == 0) ? s0 : (m == 1) ? s1 : (m == 2) ? s2
                 : (m == 3) ? s3 : (m == 4) ? s4 : s5;
  f32x4 v = *(const f32x4*)(s + e4);
  bf16x4 r;
  #pragma unroll
  for (int i = 0; i < 4; ++i) r[i] = (short)f2b(v[i]);
  *(bf16x4*)(dst + m * 16384 + e4) = r;
}

// ---------------- stage 1: LN + 5 projections + gates ----------------
__global__ __launch_bounds__(256, 4) void k_stage1(
    const float* __restrict__ x, const float* __restrict__ mask,
    const float* __restrict__ nw, const float* __restrict__ nb,
    const unsigned short* __restrict__ wb,   // [6][128][128] bf16: L,R,LG,RG,OG,O
    unsigned short* __restrict__ Lt, unsigned short* __restrict__ Rt,
    unsigned short* __restrict__ og)
{
  __shared__ unsigned short xnS[64][136];
  __shared__ float maskS[64];

  const int tid  = threadIdx.x;
  const int wave = tid >> 6, lane = tid & 63;
  const int quad = lane >> 4, l16 = lane & 15;
  const int r0 = blockIdx.x * 64;
  const int bq = r0 >> 16, iq = (r0 >> 8) & 255, j0 = r0 & 255;

  if (tid < 64) maskS[tid] = mask[r0 + tid];

  // ---- LayerNorm over D=128, 16 rows per wave (R1-proven bits) ----
  const float w0 = nw[lane], w1 = nw[lane + 64];
  const float b0 = nb[lane], b1 = nb[lane + 64];
  float v0a[16], v1a[16];
  #pragma unroll
  for (int rr = 0; rr < 16; ++rr) {
    const float* xr = x + (size_t)(r0 + wave * 16 + rr) * DD;
    v0a[rr] = xr[lane];
    v1a[rr] = xr[lane + 64];
  }
  #pragma unroll
  for (int rr = 0; rr < 16; ++rr) {
    int r = wave * 16 + rr;
    float v0 = v0a[rr], v1 = v1a[rr];
    float s = v0 + v1;
    #pragma unroll
    for (int o = 32; o; o >>= 1) s += __shfl_xor(s, o);
    float mu = s * (1.0f / 128.0f);
    float d0 = v0 - mu, d1 = v1 - mu;
    float q = d0 * d0 + d1 * d1;
    #pragma unroll
    for (int o = 32; o; o >>= 1) q += __shfl_xor(q, o);
    float rs = rsqrtf(q * (1.0f / 128.0f) + 1e-5f);
    xnS[r][lane]      = f2b(d0 * rs * w0 + b0);
    xnS[r][lane + 64] = f2b(d1 * rs * w1 + b1);
  }
  __syncthreads();   // sole barrier

  const int h0 = wave * 32;      // this wave's h-slice (2 x 16)
  const int jl = quad * 4;       // j offset within a 16-row tile (+rg)

  // gated compute: value & gate projections interleaved over kk, this
  // wave's 32-h slice, all 64 rows. Per-acc MFMA order identical to R7-R9.
  auto gatedCompute = [&](const unsigned short* __restrict__ Wv,
                          const unsigned short* __restrict__ Wg,
                          f32x4 (&aV)[4][2], f32x4 (&aG)[4][2]) {
    const unsigned short* pv = Wv + (h0 + l16) * 128 + quad * 8;
    const unsigned short* pg = Wg + (h0 + l16) * 128 + quad * 8;
    #pragma unroll
    for (int rt = 0; rt < 4; ++rt)
      #pragma unroll
      for (int n = 0; n < 2; ++n) {
        aV[rt][n] = f32x4{0.f, 0.f, 0.f, 0.f};
        aG[rt][n] = f32x4{0.f, 0.f, 0.f, 0.f};
      }
    bf16x8 bv[2], bg[2], bvn[2], bgn[2];
    #pragma unroll
    for (int n = 0; n < 2; ++n) {
      bv[n] = *(const bf16x8*)(pv + n * 2048);
      bg[n] = *(const bf16x8*)(pg + n * 2048);
    }
    #pragma unroll
    for (int kk = 0; kk < 4; ++kk) {
      if (kk < 3) {
        #pragma unroll
        for (int n = 0; n < 2; ++n) {
          bvn[n] = *(const bf16x8*)(pv + n * 2048 + (kk + 1) * 32);
          bgn[n] = *(const bf16x8*)(pg + n * 2048 + (kk + 1) * 32);
        }
      }
      #pragma unroll
      for (int rt = 0; rt < 4; ++rt) {
        bf16x8 a = *(const bf16x8*)&xnS[rt * 16 + l16][kk * 32 + quad * 8];
        #pragma unroll
        for (int n = 0; n < 2; ++n) {
          aG[rt][n] = __builtin_amdgcn_mfma_f32_16x16x32_bf16(a, bg[n], aG[rt][n], 0, 0, 0);
          aV[rt][n] = __builtin_amdgcn_mfma_f32_16x16x32_bf16(a, bv[n], aV[rt][n], 0, 0, 0);
        }
      }
      #pragma unroll
      for (int n = 0; n < 2; ++n) { bv[n] = bvn[n]; bg[n] = bgn[n]; }
    }
  };

  // gated epilogue: same formulas, direct packed 8B stores to global.
  // Layout Lt/Rt[b][h][i=iq][j]: lane owns j = rt*16+jl..+3 (contiguous)
  // at row h = h0+n*16+l16. L2 assembles full lines (block covers all j).
  auto gatedStore = [&](f32x4 (&aV)[4][2], f32x4 (&aG)[4][2],
                        unsigned short* __restrict__ dstBase) {
    #pragma unroll
    for (int rt = 0; rt < 4; ++rt)
      #pragma unroll
      for (int n = 0; n < 2; ++n) {
        bf16x4 p;
        #pragma unroll
        for (int rg = 0; rg < 4; ++rg) {
          float g = sigmoidf_(aG[rt][n][rg]);
          p[rg] = (short)f2b(aV[rt][n][rg] * maskS[rt * 16 + jl + rg] * g);
        }
        *(bf16x4*)(dstBase +
            (((size_t)bq * 128 + h0 + n * 16 + l16) * 256 + iq) * 256 +
            j0 + rt * 16 + jl) = p;
      }
  };

  f32x4 aV[4][2], aG[4][2];

  // ---- LEFT ----
  gatedCompute(wb + 0 * 16384, wb + 2 * 16384, aV, aG);
  gatedStore(aV, aG, Lt);
  // ---- RIGHT ----
  gatedCompute(wb + 1 * 16384, wb + 3 * 16384, aV, aG);
  gatedStore(aV, aG, Rt);

  // ---- OUT GATE (operand-swapped: lane owns 4 consecutive h at j=l16) ----
  {
    const unsigned short* po = wb + 4 * 16384 + (h0 + l16) * 128 + quad * 8;
    f32x4 aO[4][2];
    #pragma unroll
    for (int rt = 0; rt < 4; ++rt)
      #pragma unroll
      for (int n = 0; n < 2; ++n) aO[rt][n] = f32x4{0.f, 0.f, 0.f, 0.f};
    bf16x8 bo[2], bon[2];
    #pragma unroll
    for (int n = 0; n < 2; ++n) bo[n] = *(const bf16x8*)(po + n * 2048);
    #pragma unroll
    for (int kk = 0; kk < 4; ++kk) {
      if (kk < 3) {
        #pragma unroll
        for (int n = 0; n < 2; ++n)
          bon[n] = *(const bf16x8*)(po + n * 2048 + (kk + 1) * 32);
      }
      #pragma unroll
      for (int rt = 0; rt < 4; ++rt) {
        bf16x8 a = *(const bf16x8*)&xnS[rt * 16 + l16][kk * 32 + quad * 8];
        #pragma unroll
        for (int n = 0; n < 2; ++n)
          aO[rt][n] = __builtin_amdgcn_mfma_f32_16x16x32_bf16(bo[n], a, aO[rt][n], 0, 0, 0);
      }
      #pragma unroll
      for (int n = 0; n < 2; ++n) bo[n] = bon[n];
    }
    // direct store: og[(r0 + j)*128 + h], j = rt*16+l16, h = h0+n*16+quad*4..+3
    #pragma unroll
    for (int rt = 0; rt < 4; ++rt)
      #pragma unroll
      for (int n = 0; n < 2; ++n) {
        bf16x4 p;
        #pragma unroll
        for (int rg = 0; rg < 4; ++rg)
          p[rg] = (short)f2b(sigmoidf_(aO[rt][n][rg]));
        *(bf16x4*)(og + (size_t)(r0 + rt * 16 + l16) * HH +
                   h0 + n * 16 + quad * 4) = p;
      }
  }
}

// ---------------- stage 2: batched 256x256x256 A.B^T per (b,h) ----------------
__global__ __launch_bounds__(256, 4) void k_stage2(
    const unsigned short* __restrict__ Lt, const unsigned short* __restrict__ Rt,
    unsigned short* __restrict__ Tt)
{
  __shared__ unsigned short As[128][72];
  __shared__ unsigned short Bs[128][72];

  const int tid  = threadIdx.x;
  const int wave = tid >> 6, lane = tid & 63;
  const int quad = lane >> 4, l16 = lane & 15;

  // XCD-pairing swizzle (R8): jt=0/1 pair of one (bh,it) share an XCD L2.
  const int w   = blockIdx.y * 4 + blockIdx.x;
  const int grp = w >> 4;
  const int xcd = w & 7;
  const int jt  = (w >> 3) & 1;
  const int pid = grp * 8 + xcd;      // [0,512)
  const int bh  = pid >> 1;
  const int it  = pid & 1;

  const unsigned short* A  = Lt + (size_t)bh * 65536 + it * 128 * 256;
  const unsigned short* Bp = Rt + (size_t)bh * 65536 + jt * 128 * 256;

  f32x4 acc[2][8];
  #pragma unroll
  for (int mt = 0; mt < 2; ++mt)
    #pragma unroll
    for (int nt = 0; nt < 8; ++nt) acc[mt][nt] = f32x4{0.f, 0.f, 0.f, 0.f};

  const int srow = tid >> 3, sc8 = tid & 7;

  // reg-staged pipeline: chunk ks lives in ra/rb while chunk ks-1 computes
  bf16x8 ra[4], rb[4];
  #pragma unroll
  for (int i = 0; i < 4; ++i) {
    ra[i] = *(const bf16x8*)(A  + (i * 32 + srow) * 256 + sc8 * 8);
    rb[i] = *(const bf16x8*)(Bp + (i * 32 + srow) * 256 + sc8 * 8);
  }

  #pragma unroll
  for (int ks = 0; ks < 4; ++ks) {
    #pragma unroll
    for (int i = 0; i < 4; ++i) {
      *(bf16x8*)&As[i * 32 + srow][sc8 * 8] = ra[i];
      *(bf16x8*)&Bs[i * 32 + srow][sc8 * 8] = rb[i];
    }
    __syncthreads();
    if (ks < 3) {   // issue next chunk now; latency hides under MFMA below
      #pragma unroll
      for (int i = 0; i < 4; ++i) {
        ra[i] = *(const bf16x8*)(A  + (i * 32 + srow) * 256 + (ks + 1) * 64 + sc8 * 8);
        rb[i] = *(const bf16x8*)(Bp + (i * 32 + srow) * 256 + (ks + 1) * 64 + sc8 * 8);
      }
    }
    // operand-swapped: first op = Rt frag (j), second = Lt frag (i).
    // Same products, same k-order -> same bits, C transposed:
    // j <- wave*32+mt*16+quad*4+rg, i <- nt*16+l16.
    #pragma unroll
    for (int k2 = 0; k2 < 2; ++k2) {
      int ko = k2 * 32 + quad * 8;
      bf16x8 r0f = *(const bf16x8*)&Bs[wave * 32 + l16][ko];
      bf16x8 r1f = *(const bf16x8*)&Bs[wave * 32 + 16 + l16][ko];
      #pragma unroll
      for (int nt = 0; nt < 8; ++nt) {
        bf16x8 lf = *(const bf16x8*)&As[nt * 16 + l16][ko];
        acc[0][nt] = __builtin_amdgcn_mfma_f32_16x16x32_bf16(r0f, lf, acc[0][nt], 0, 0, 0);
        acc[1][nt] = __builtin_amdgcn_mfma_f32_16x16x32_bf16(r1f, lf, acc[1][nt], 0, 0, 0);
      }
    }
    __syncthreads();
  }

  // packed 8B stores: lane owns 4 consecutive j at row i = nt*16+l16
  unsigned short* C = Tt + (size_t)bh * 65536 + it * 128 * 256 + jt * 128;
  #pragma unroll
  for (int mt = 0; mt < 2; ++mt)
    #pragma unroll
    for (int nt = 0; nt < 8; ++nt) {
      bf16x4 p;
      #pragma unroll
      for (int rg = 0; rg < 4; ++rg) p[rg] = (short)f2b(acc[mt][nt][rg]);
      *(bf16x4*)&C[(nt * 16 + l16) * 256 + wave * 32 + mt * 16 + quad * 4] = p;
    }
}

// ---------------- stage 3: LN over h * gate, @ w_out^T ----------------
__global__ __launch_bounds__(256, 4) void k_stage3(
    const unsigned short* __restrict__ Tt, const unsigned short* __restrict__ og,
    const float* __restrict__ onw, const float* __restrict__ onb,
    const unsigned short* __restrict__ wbO, float* __restrict__ out)
{
  __shared__ unsigned short tS[128][72];    // [h][j-swizzled] tri tile
  __shared__ unsigned short vS[64][136];    // [j][h]
  __shared__ float onwS[128], onbS[128];

  const int tid  = threadIdx.x;
  const int wave = tid >> 6, lane = tid & 63;
  const int quad = lane >> 4, l16 = lane & 15;
  const int r0 = blockIdx.x * 64;
  const int bq = r0 >> 16, iq = (r0 >> 8) & 255, j0 = r0 & 255;
  const int jw = wave * 16;                 // this wave's private j rows

  // early og prefetch for this lane's elementwise slice (hidden latency)
  const int jE = jw + (lane >> 2), hq = lane & 3;
  bf16x8 gpre[4];
  {
    const unsigned short* ogp = og + (size_t)(r0 + jE) * HH + hq * 32;
    #pragma unroll
    for (int c = 0; c < 4; ++c) gpre[c] = *(const bf16x8*)(ogp + c * 8);
  }

  if (tid < 128) { onwS[tid] = onw[tid]; onbS[tid] = onb[tid]; }

  // load tri tile [128 h][64 j]; j-block (j>>3) XOR'd with (h>>5)&3 so the
  // transpose read's 4 row-groups hit different banks (pure addr permutation)
  {
    int h = tid >> 1, half = tid & 1;
    int g = (h >> 5) & 3;
    const bf16x8* s = (const bf16x8*)(Tt +
        ((((size_t)bq * 128 + h) * 256 + iq) * 256 + j0 + half * 32));
    #pragma unroll
    for (int c = 0; c < 4; ++c)
      *(bf16x8*)&tS[h][((half * 4 + c) ^ g) << 3] = s[c];
  }
  __syncthreads();   // sole block-wide barrier

  // ---- wave-private from here on: wave owns j in [jw, jw+16) ----
  // transpose tS[h][j] -> vS[j][h] for the wave's 16 j (bit moves only)
  {
    int j  = jw + (lane & 15);
    int g2 = (lane >> 4) & 3;                // == (row>>5)&3 for this lane
    int hb = (lane >> 4) * 32;
    int jc = (((j >> 3) ^ g2) << 3) | (j & 7);
    #pragma unroll
    for (int c = 0; c < 4; ++c) {
      bf16x8 t;
      #pragma unroll
      for (int e = 0; e < 8; ++e) t[e] = (short)tS[hb + c * 8 + e][jc];
      *(bf16x8*)&vS[j][hb + c * 8] = t;
    }
  }
  asm volatile("s_waitcnt lgkmcnt(0)" ::: "memory");

  // stats: identical h-order summation & shfl pairing as before.
  float mu, rs;
  {
    int j = jw + ((lane & 31) >> 1), h0 = (lane & 1) * 64;
    float s = 0.f, q = 0.f;
    #pragma unroll
    for (int c = 0; c < 8; ++c) {
      bf16x8 v8 = *(const bf16x8*)&vS[j][h0 + c * 8];
      #pragma unroll
      for (int e = 0; e < 8; ++e) {
        float v = b2f((unsigned short)v8[e]);
        s += v; q += v * v;
      }
    }
    s += __shfl_xor(s, 1);
    q += __shfl_xor(q, 1);
    mu = s * (1.0f / 128.0f);
    float var = q * (1.0f / 128.0f) - mu * mu;
    rs = rsqrtf(var + 1e-5f);
  }
  mu = __shfl(mu, (jE - jw) << 1);
  rs = __shfl(rs, (jE - jw) << 1);

  // elementwise normalize * gate (same formulas), wave-private rows
  {
    unsigned short* vp = &vS[jE][hq * 32];
    #pragma unroll
    for (int c = 0; c < 4; ++c) {
      bf16x8 tv = *(bf16x8*)&vp[c * 8];
      bf16x8 gv = gpre[c];
      bf16x8 r;
      #pragma unroll
      for (int e = 0; e < 8; ++e) {
        int hh = hq * 32 + c * 8 + e;
        float v = (b2f((unsigned short)tv[e]) - mu) * rs * onwS[hh] + onbS[hh];
        r[e] = (short)f2b(v * b2f((unsigned short)gv[e]));
      }
      *(bf16x8*)&vp[c * 8] = r;
    }
  }
  asm volatile("s_waitcnt lgkmcnt(0)" ::: "memory");

  // out[j][d] = vS[j][:] @ w_out^T  (wave's 16 rows)
  // operand-swapped: first op = w_out frag (d), second = vS frag (j).
  // d <- nt*16+quad*4+rg (4 consecutive -> dwordx4 store), j <- jw+l16.
  f32x4 acc[8];
  #pragma unroll
  for (int nt = 0; nt < 8; ++nt) acc[nt] = f32x4{0.f, 0.f, 0.f, 0.f};
  #pragma unroll
  for (int kk = 0; kk < 4; ++kk) {
    bf16x8 xv = *(const bf16x8*)&vS[jw + l16][kk * 32 + quad * 8];
    #pragma unroll
    for (int nt = 0; nt < 8; ++nt) {
      bf16x8 wv = *(const bf16x8*)(wbO + (nt * 16 + l16) * 128 + kk * 32 + quad * 8);
      acc[nt] = __builtin_amdgcn_mfma_f32_16x16x32_bf16(wv, xv, acc[nt], 0, 0, 0);
    }
  }
  #pragma unroll
  for (int nt = 0; nt < 8; ++nt)
    *(f32x4*)&out[(size_t)(r0 + jw + l16) * DD + nt * 16 + quad * 4] = acc[nt];
}

extern "C" void kernel_launch(void* const* d_in, const int* in_sizes, int n_in,
                              void* d_out, int out_size, void* d_ws, size_t ws_size,
                              hipStream_t stream)
{
  const float* x    = (const float*)d_in[0];
  const float* mask = (const float*)d_in[1];
  const float* nw   = (const float*)d_in[2];
  const float* nb   = (const float*)d_in[3];
  const float* wL   = (const float*)d_in[4];
  const float* wR   = (const float*)d_in[5];
  const float* wLG  = (const float*)d_in[6];
  const float* wRG  = (const float*)d_in[7];
  const float* wOG  = (const float*)d_in[8];
  const float* onw  = (const float*)d_in[9];
  const float* onb  = (const float*)d_in[10];
  const float* wO   = (const float*)d_in[11];

  char* ws = (char*)d_ws;
  unsigned short* wb = (unsigned short*)ws;
  unsigned short* og = (unsigned short*)(ws + (1 << 18));
  unsigned short* Lt = (unsigned short*)(ws + (1 << 18) + 1 * (size_t)(1 << 25));
  unsigned short* Rt = (unsigned short*)(ws + (1 << 18) + 2 * (size_t)(1 << 25));
  unsigned short* Tt = (unsigned short*)(ws + (1 << 18) + 3 * (size_t)(1 << 25));

  k_cvt<<<24, 1024, 0, stream>>>(wL, wR, wLG, wRG, wOG, wO, wb);
  k_stage1<<<2048, 256, 0, stream>>>(x, mask, nw, nb, wb, Lt, Rt, og);
  k_stage2<<<dim3(4, 256), 256, 0, stream>>>(Lt, Rt, Tt);
  k_stage3<<<2048, 256, 0, stream>>>(Tt, og, onw, onb, wb + 5 * 16384, (float*)d_out);
}

// Round 7
// 267.736 us; speedup vs baseline: 2.2112x; 1.1989x over previous
//
#include <hip/hip_runtime.h>

// TriMul: B=2, S=256, DIM=128, HID=128
// R1-proven arithmetic (absmax 1.17e-2, bit-stable since R4). R13 =
// verbatim restore of the R9/R3 champion (267.87us measured):
//  - R10 fusion (-2x), R11 launch-bounds spill (-4.6x), R12 direct
//    stores (write amplification 2.7x) all post-mortem'd and reverted.
//  - oS LDS staging in stage1 is LOAD-BEARING: it converts the wave's
//    scattered 8B register ownership into dense per-thread 64B stores.
//  - stage1: h-sliced waves, interleaved gate+value MFMA, kk-pipelined
//    B prefetch, 6 barriers, 36KB LDS, 4 blocks/CU (VGPR 64, no spill).
//  - stage2: reg-staged prefetch + XCD-pairing swizzle, LDS 128-tile.
//  - stage3: single barrier, wave-private transpose/stats/elementwise/
//    GEMM, operand-swapped out-GEMM with dwordx4 stores.
// HARD RULE (R2/R3): never touch arithmetic statements, value-producing
// operand order semantics, reduction pairing, or sigmoid form. absmax
// must stay exactly 0.01171875.

#define SS 256
#define DD 128
#define HH 128

typedef __attribute__((ext_vector_type(8))) short bf16x8;
typedef __attribute__((ext_vector_type(4))) short bf16x4;
typedef __attribute__((ext_vector_type(4))) float f32x4;

__device__ __forceinline__ unsigned short f2b(float f) {
  unsigned u = __builtin_bit_cast(unsigned, f);
  u = (u + 0x7FFFu + ((u >> 16) & 1u)) >> 16;
  return (unsigned short)u;
}
__device__ __forceinline__ float b2f(unsigned short h) {
  return __builtin_bit_cast(float, ((unsigned)h) << 16);
}
__device__ __forceinline__ float sigmoidf_(float x) {
  return 1.0f / (1.0f + expf(-x));
}

// ---------------- stage 0: weight fp32 -> bf16 (x4 vectorized) ----------------
__global__ __launch_bounds__(1024) void k_cvt(
    const float* __restrict__ s0, const float* __restrict__ s1,
    const float* __restrict__ s2, const float* __restrict__ s3,
    const float* __restrict__ s4, const float* __restrict__ s5,
    unsigned short* __restrict__ dst)
{
  int m = blockIdx.x >> 2;
  int e4 = (((blockIdx.x & 3) << 10) | threadIdx.x) << 2;
  const float* s = (m == 0) ? s0 : (m == 1) ? s1 : (m == 2) ? s2
                 : (m == 3) ? s3 : (m == 4) ? s4 : s5;
  f32x4 v = *(const f32x4*)(s + e4);
  bf16x4 r;
  #pragma unroll
  for (int i = 0; i < 4; ++i) r[i] = (short)f2b(v[i]);
  *(bf16x4*)(dst + m * 16384 + e4) = r;
}

// ---------------- stage 1: LN + 5 projections + gates ----------------
__global__ __launch_bounds__(256, 4) void k_stage1(
    const float* __restrict__ x, const float* __restrict__ mask,
    const float* __restrict__ nw, const float* __restrict__ nb,
    const unsigned short* __restrict__ wb,   // [6][128][128] bf16: L,R,LG,RG,OG,O
    unsigned short* __restrict__ Lt, unsigned short* __restrict__ Rt,
    unsigned short* __restrict__ og)
{
  __shared__ unsigned short xnS[64][136];
  __shared__ unsigned short oS[128][72];
  __shared__ float maskS[64];

  const int tid  = threadIdx.x;
  const int wave = tid >> 6, lane = tid & 63;
  const int quad = lane >> 4, l16 = lane & 15;
  const int r0 = blockIdx.x * 64;
  const int bq = r0 >> 16, iq = (r0 >> 8) & 255, j0 = r0 & 255;

  if (tid < 64) maskS[tid] = mask[r0 + tid];

  // ---- LayerNorm over D=128, 16 rows per wave (R1-proven bits) ----
  const float w0 = nw[lane], w1 = nw[lane + 64];
  const float b0 = nb[lane], b1 = nb[lane + 64];
  float v0a[16], v1a[16];
  #pragma unroll
  for (int rr = 0; rr < 16; ++rr) {
    const float* xr = x + (size_t)(r0 + wave * 16 + rr) * DD;
    v0a[rr] = xr[lane];
    v1a[rr] = xr[lane + 64];
  }
  #pragma unroll
  for (int rr = 0; rr < 16; ++rr) {
    int r = wave * 16 + rr;
    float v0 = v0a[rr], v1 = v1a[rr];
    float s = v0 + v1;
    #pragma unroll
    for (int o = 32; o; o >>= 1) s += __shfl_xor(s, o);
    float mu = s * (1.0f / 128.0f);
    float d0 = v0 - mu, d1 = v1 - mu;
    float q = d0 * d0 + d1 * d1;
    #pragma unroll
    for (int o = 32; o; o >>= 1) q += __shfl_xor(q, o);
    float rs = rsqrtf(q * (1.0f / 128.0f) + 1e-5f);
    xnS[r][lane]      = f2b(d0 * rs * w0 + b0);
    xnS[r][lane + 64] = f2b(d1 * rs * w1 + b1);
  }
  __syncthreads();

  const int h0 = wave * 32;      // this wave's h-slice (2 x 16)
  const int jl = quad * 4;       // j offset within a 16-row tile (+rg)

  auto coopStore = [&](unsigned short* dstBase) {
    int h = tid >> 1, half = tid & 1;
    const bf16x8* s = (const bf16x8*)&oS[h][half * 32];
    bf16x8* d = (bf16x8*)(dstBase +
        ((((size_t)bq * 128 + h) * 256 + iq) * 256 + j0 + half * 32));
    d[0] = s[0]; d[1] = s[1]; d[2] = s[2]; d[3] = s[3];
  };

  // gated compute: value & gate projections interleaved over kk, this
  // wave's 32-h slice, all 64 rows. Per-acc MFMA order identical to R7/R8.
  auto gatedCompute = [&](const unsigned short* __restrict__ Wv,
                          const unsigned short* __restrict__ Wg,
                          f32x4 (&aV)[4][2], f32x4 (&aG)[4][2]) {
    const unsigned short* pv = Wv + (h0 + l16) * 128 + quad * 8;
    const unsigned short* pg = Wg + (h0 + l16) * 128 + quad * 8;
    #pragma unroll
    for (int rt = 0; rt < 4; ++rt)
      #pragma unroll
      for (int n = 0; n < 2; ++n) {
        aV[rt][n] = f32x4{0.f, 0.f, 0.f, 0.f};
        aG[rt][n] = f32x4{0.f, 0.f, 0.f, 0.f};
      }
    bf16x8 bv[2], bg[2], bvn[2], bgn[2];
    #pragma unroll
    for (int n = 0; n < 2; ++n) {
      bv[n] = *(const bf16x8*)(pv + n * 2048);
      bg[n] = *(const bf16x8*)(pg + n * 2048);
    }
    #pragma unroll
    for (int kk = 0; kk < 4; ++kk) {
      if (kk < 3) {
        #pragma unroll
        for (int n = 0; n < 2; ++n) {
          bvn[n] = *(const bf16x8*)(pv + n * 2048 + (kk + 1) * 32);
          bgn[n] = *(const bf16x8*)(pg + n * 2048 + (kk + 1) * 32);
        }
      }
      #pragma unroll
      for (int rt = 0; rt < 4; ++rt) {
        bf16x8 a = *(const bf16x8*)&xnS[rt * 16 + l16][kk * 32 + quad * 8];
        #pragma unroll
        for (int n = 0; n < 2; ++n) {
          aG[rt][n] = __builtin_amdgcn_mfma_f32_16x16x32_bf16(a, bg[n], aG[rt][n], 0, 0, 0);
          aV[rt][n] = __builtin_amdgcn_mfma_f32_16x16x32_bf16(a, bv[n], aV[rt][n], 0, 0, 0);
        }
      }
      #pragma unroll
      for (int n = 0; n < 2; ++n) { bv[n] = bvn[n]; bg[n] = bgn[n]; }
    }
  };

  // gated epilogue: same formulas, b64-packed LDS writes (rg = j contiguous)
  auto gatedEpilogue = [&](f32x4 (&aV)[4][2], f32x4 (&aG)[4][2]) {
    #pragma unroll
    for (int rt = 0; rt < 4; ++rt)
      #pragma unroll
      for (int n = 0; n < 2; ++n) {
        bf16x4 p;
        #pragma unroll
        for (int rg = 0; rg < 4; ++rg) {
          float g = sigmoidf_(aG[rt][n][rg]);
          p[rg] = (short)f2b(aV[rt][n][rg] * maskS[rt * 16 + jl + rg] * g);
        }
        *(bf16x4*)&oS[h0 + n * 16 + l16][rt * 16 + jl] = p;
      }
  };

  f32x4 aV[4][2], aG[4][2];

  // ---- LEFT ----
  gatedCompute(wb + 0 * 16384, wb + 2 * 16384, aV, aG);
  gatedEpilogue(aV, aG);
  __syncthreads();
  coopStore(Lt);
  // ---- RIGHT compute overlapped with Lt store ----
  gatedCompute(wb + 1 * 16384, wb + 3 * 16384, aV, aG);
  __syncthreads();            // all coopStore(Lt) reads of oS done
  gatedEpilogue(aV, aG);
  __syncthreads();
  coopStore(Rt);

  // ---- OUT GATE (operand-swapped: h <- quad*4+rg, j <- l16) ----
  {
    const unsigned short* po = wb + 4 * 16384 + (h0 + l16) * 128 + quad * 8;
    f32x4 aO[4][2];
    #pragma unroll
    for (int rt = 0; rt < 4; ++rt)
      #pragma unroll
      for (int n = 0; n < 2; ++n) aO[rt][n] = f32x4{0.f, 0.f, 0.f, 0.f};
    bf16x8 bo[2], bon[2];
    #pragma unroll
    for (int n = 0; n < 2; ++n) bo[n] = *(const bf16x8*)(po + n * 2048);
    #pragma unroll
    for (int kk = 0; kk < 4; ++kk) {
      if (kk < 3) {
        #pragma unroll
        for (int n = 0; n < 2; ++n)
          bon[n] = *(const bf16x8*)(po + n * 2048 + (kk + 1) * 32);
      }
      #pragma unroll
      for (int rt = 0; rt < 4; ++rt) {
        bf16x8 a = *(const bf16x8*)&xnS[rt * 16 + l16][kk * 32 + quad * 8];
        #pragma unroll
        for (int n = 0; n < 2; ++n)
          aO[rt][n] = __builtin_amdgcn_mfma_f32_16x16x32_bf16(bo[n], a, aO[rt][n], 0, 0, 0);
      }
      #pragma unroll
      for (int n = 0; n < 2; ++n) bo[n] = bon[n];
    }
    __syncthreads();          // all coopStore(Rt) reads of oS done
    // epilogue: lane owns 4 consecutive h at fixed j -> b64 packed
    unsigned short* ogS = &oS[0][0];
    #pragma unroll
    for (int rt = 0; rt < 4; ++rt)
      #pragma unroll
      for (int n = 0; n < 2; ++n) {
        bf16x4 p;
        #pragma unroll
        for (int rg = 0; rg < 4; ++rg)
          p[rg] = (short)f2b(sigmoidf_(aO[rt][n][rg]));
        *(bf16x4*)&ogS[(rt * 16 + l16) * 136 + h0 + n * 16 + quad * 4] = p;
      }
  }
  __syncthreads();
  {
    int j = tid >> 2, qq = tid & 3;
    const unsigned short* ogS = &oS[0][0];
    const bf16x8* sp = (const bf16x8*)&ogS[j * 136 + qq * 32];
    bf16x8* d = (bf16x8*)(og + (size_t)(r0 + j) * HH + qq * 32);
    d[0] = sp[0]; d[1] = sp[1]; d[2] = sp[2]; d[3] = sp[3];
  }
}

// ---------------- stage 2: batched 256x256x256 A.B^T per (b,h) ----------------
__global__ __launch_bounds__(256, 4) void k_stage2(
    const unsigned short* __restrict__ Lt, const unsigned short* __restrict__ Rt,
    unsigned short* __restrict__ Tt)
{
  __shared__ unsigned short As[128][72];
  __shared__ unsigned short Bs[128][72];

  const int tid  = threadIdx.x;
  const int wave = tid >> 6, lane = tid & 63;
  const int quad = lane >> 4, l16 = lane & 15;

  // XCD-pairing swizzle (R8): jt=0/1 pair of one (bh,it) share an XCD L2.
  const int w   = blockIdx.y * 4 + blockIdx.x;
  const int grp = w >> 4;
  const int xcd = w & 7;
  const int jt  = (w >> 3) & 1;
  const int pid = grp * 8 + xcd;      // [0,512)
  const int bh  = pid >> 1;
  const int it  = pid & 1;

  const unsigned short* A  = Lt + (size_t)bh * 65536 + it * 128 * 256;
  const unsigned short* Bp = Rt + (size_t)bh * 65536 + jt * 128 * 256;

  f32x4 acc[2][8];
  #pragma unroll
  for (int mt = 0; mt < 2; ++mt)
    #pragma unroll
    for (int nt = 0; nt < 8; ++nt) acc[mt][nt] = f32x4{0.f, 0.f, 0.f, 0.f};

  const int srow = tid >> 3, sc8 = tid & 7;

  // reg-staged pipeline: chunk ks lives in ra/rb while chunk ks-1 computes
  bf16x8 ra[4], rb[4];
  #pragma unroll
  for (int i = 0; i < 4; ++i) {
    ra[i] = *(const bf16x8*)(A  + (i * 32 + srow) * 256 + sc8 * 8);
    rb[i] = *(const bf16x8*)(Bp + (i * 32 + srow) * 256 + sc8 * 8);
  }

  #pragma unroll
  for (int ks = 0; ks < 4; ++ks) {
    #pragma unroll
    for (int i = 0; i < 4; ++i) {
      *(bf16x8*)&As[i * 32 + srow][sc8 * 8] = ra[i];
      *(bf16x8*)&Bs[i * 32 + srow][sc8 * 8] = rb[i];
    }
    __syncthreads();
    if (ks < 3) {   // issue next chunk now; latency hides under MFMA below
      #pragma unroll
      for (int i = 0; i < 4; ++i) {
        ra[i] = *(const bf16x8*)(A  + (i * 32 + srow) * 256 + (ks + 1) * 64 + sc8 * 8);
        rb[i] = *(const bf16x8*)(Bp + (i * 32 + srow) * 256 + (ks + 1) * 64 + sc8 * 8);
      }
    }
    // operand-swapped: first op = Rt frag (j), second = Lt frag (i).
    // Same products, same k-order -> same bits, C transposed:
    // j <- wave*32+mt*16+quad*4+rg, i <- nt*16+l16.
    #pragma unroll
    for (int k2 = 0; k2 < 2; ++k2) {
      int ko = k2 * 32 + quad * 8;
      bf16x8 r0f = *(const bf16x8*)&Bs[wave * 32 + l16][ko];
      bf16x8 r1f = *(const bf16x8*)&Bs[wave * 32 + 16 + l16][ko];
      #pragma unroll
      for (int nt = 0; nt < 8; ++nt) {
        bf16x8 lf = *(const bf16x8*)&As[nt * 16 + l16][ko];
        acc[0][nt] = __builtin_amdgcn_mfma_f32_16x16x32_bf16(r0f, lf, acc[0][nt], 0, 0, 0);
        acc[1][nt] = __builtin_amdgcn_mfma_f32_16x16x32_bf16(r1f, lf, acc[1][nt], 0, 0, 0);
      }
    }
    __syncthreads();
  }

  // packed 8B stores: lane owns 4 consecutive j at row i = nt*16+l16
  unsigned short* C = Tt + (size_t)bh * 65536 + it * 128 * 256 + jt * 128;
  #pragma unroll
  for (int mt = 0; mt < 2; ++mt)
    #pragma unroll
    for (int nt = 0; nt < 8; ++nt) {
      bf16x4 p;
      #pragma unroll
      for (int rg = 0; rg < 4; ++rg) p[rg] = (short)f2b(acc[mt][nt][rg]);
      *(bf16x4*)&C[(nt * 16 + l16) * 256 + wave * 32 + mt * 16 + quad * 4] = p;
    }
}

// ---------------- stage 3: LN over h * gate, @ w_out^T ----------------
__global__ __launch_bounds__(256, 4) void k_stage3(
    const unsigned short* __restrict__ Tt, const unsigned short* __restrict__ og,
    const float* __restrict__ onw, const float* __restrict__ onb,
    const unsigned short* __restrict__ wbO, float* __restrict__ out)
{
  __shared__ unsigned short tS[128][72];    // [h][j-swizzled] tri tile
  __shared__ unsigned short vS[64][136];    // [j][h]
  __shared__ float onwS[128], onbS[128];

  const int tid  = threadIdx.x;
  const int wave = tid >> 6, lane = tid & 63;
  const int quad = lane >> 4, l16 = lane & 15;
  const int r0 = blockIdx.x * 64;
  const int bq = r0 >> 16, iq = (r0 >> 8) & 255, j0 = r0 & 255;
  const int jw = wave * 16;                 // this wave's private j rows

  // early og prefetch for this lane's elementwise slice (hidden latency)
  const int jE = jw + (lane >> 2), hq = lane & 3;
  bf16x8 gpre[4];
  {
    const unsigned short* ogp = og + (size_t)(r0 + jE) * HH + hq * 32;
    #pragma unroll
    for (int c = 0; c < 4; ++c) gpre[c] = *(const bf16x8*)(ogp + c * 8);
  }

  if (tid < 128) { onwS[tid] = onw[tid]; onbS[tid] = onb[tid]; }

  // load tri tile [128 h][64 j]; j-block (j>>3) XOR'd with (h>>5)&3 so the
  // transpose read's 4 row-groups hit different banks (pure addr permutation)
  {
    int h = tid >> 1, half = tid & 1;
    int g = (h >> 5) & 3;
    const bf16x8* s = (const bf16x8*)(Tt +
        ((((size_t)bq * 128 + h) * 256 + iq) * 256 + j0 + half * 32));
    #pragma unroll
    for (int c = 0; c < 4; ++c)
      *(bf16x8*)&tS[h][((half * 4 + c) ^ g) << 3] = s[c];
  }
  __syncthreads();   // sole block-wide barrier

  // ---- wave-private from here on: wave owns j in [jw, jw+16) ----
  // transpose tS[h][j] -> vS[j][h] for the wave's 16 j (bit moves only)
  {
    int j  = jw + (lane & 15);
    int g2 = (lane >> 4) & 3;                // == (row>>5)&3 for this lane
    int hb = (lane >> 4) * 32;
    int jc = (((j >> 3) ^ g2) << 3) | (j & 7);
    #pragma unroll
    for (int c = 0; c < 4; ++c) {
      bf16x8 t;
      #pragma unroll
      for (int e = 0; e < 8; ++e) t[e] = (short)tS[hb + c * 8 + e][jc];
      *(bf16x8*)&vS[j][hb + c * 8] = t;
    }
  }
  asm volatile("s_waitcnt lgkmcnt(0)" ::: "memory");

  // stats: identical h-order summation & shfl pairing as before.
  float mu, rs;
  {
    int j = jw + ((lane & 31) >> 1), h0 = (lane & 1) * 64;
    float s = 0.f, q = 0.f;
    #pragma unroll
    for (int c = 0; c < 8; ++c) {
      bf16x8 v8 = *(const bf16x8*)&vS[j][h0 + c * 8];
      #pragma unroll
      for (int e = 0; e < 8; ++e) {
        float v = b2f((unsigned short)v8[e]);
        s += v; q += v * v;
      }
    }
    s += __shfl_xor(s, 1);
    q += __shfl_xor(q, 1);
    mu = s * (1.0f / 128.0f);
    float var = q * (1.0f / 128.0f) - mu * mu;
    rs = rsqrtf(var + 1e-5f);
  }
  mu = __shfl(mu, (jE - jw) << 1);
  rs = __shfl(rs, (jE - jw) << 1);

  // elementwise normalize * gate (same formulas), wave-private rows
  {
    unsigned short* vp = &vS[jE][hq * 32];
    #pragma unroll
    for (int c = 0; c < 4; ++c) {
      bf16x8 tv = *(bf16x8*)&vp[c * 8];
      bf16x8 gv = gpre[c];
      bf16x8 r;
      #pragma unroll
      for (int e = 0; e < 8; ++e) {
        int hh = hq * 32 + c * 8 + e;
        float v = (b2f((unsigned short)tv[e]) - mu) * rs * onwS[hh] + onbS[hh];
        r[e] = (short)f2b(v * b2f((unsigned short)gv[e]));
      }
      *(bf16x8*)&vp[c * 8] = r;
    }
  }
  asm volatile("s_waitcnt lgkmcnt(0)" ::: "memory");

  // out[j][d] = vS[j][:] @ w_out^T  (wave's 16 rows)
  // operand-swapped: first op = w_out frag (d), second = vS frag (j).
  // d <- nt*16+quad*4+rg (4 consecutive -> dwordx4 store), j <- jw+l16.
  f32x4 acc[8];
  #pragma unroll
  for (int nt = 0; nt < 8; ++nt) acc[nt] = f32x4{0.f, 0.f, 0.f, 0.f};
  #pragma unroll
  for (int kk = 0; kk < 4; ++kk) {
    bf16x8 xv = *(const bf16x8*)&vS[jw + l16][kk * 32 + quad * 8];
    #pragma unroll
    for (int nt = 0; nt < 8; ++nt) {
      bf16x8 wv = *(const bf16x8*)(wbO + (nt * 16 + l16) * 128 + kk * 32 + quad * 8);
      acc[nt] = __builtin_amdgcn_mfma_f32_16x16x32_bf16(wv, xv, acc[nt], 0, 0, 0);
    }
  }
  #pragma unroll
  for (int nt = 0; nt < 8; ++nt)
    *(f32x4*)&out[(size_t)(r0 + jw + l16) * DD + nt * 16 + quad * 4] = acc[nt];
}

extern "C" void kernel_launch(void* const* d_in, const int* in_sizes, int n_in,
                              void* d_out, int out_size, void* d_ws, size_t ws_size,
                              hipStream_t stream)
{
  const float* x    = (const float*)d_in[0];
  const float* mask = (const float*)d_in[1];
  const float* nw   = (const float*)d_in[2];
  const float* nb   = (const float*)d_in[3];
  const float* wL   = (const float*)d_in[4];
  const float* wR   = (const float*)d_in[5];
  const float* wLG  = (const float*)d_in[6];
  const float* wRG  = (const float*)d_in[7];
  const float* wOG  = (const float*)d_in[8];
  const float* onw  = (const float*)d_in[9];
  const float* onb  = (const float*)d_in[10];
  const float* wO   = (const float*)d_in[11];

  char* ws = (char*)d_ws;
  unsigned short* wb = (unsigned short*)ws;
  unsigned short* og = (unsigned short*)(ws + (1 << 18));
  unsigned short* Lt = (unsigned short*)(ws + (1 << 18) + 1 * (size_t)(1 << 25));
  unsigned short* Rt = (unsigned short*)(ws + (1 << 18) + 2 * (size_t)(1 << 25));
  unsigned short* Tt = (unsigned short*)(ws + (1 << 18) + 3 * (size_t)(1 << 25));

  k_cvt<<<24, 1024, 0, stream>>>(wL, wR, wLG, wRG, wOG, wO, wb);
  k_stage1<<<2048, 256, 0, stream>>>(x, mask, nw, nb, wb, Lt, Rt, og);
  k_stage2<<<dim3(4, 256), 256, 0, stream>>>(Lt, Rt, Tt);
  k_stage3<<<2048, 256, 0, stream>>>(Tt, og, onw, onb, wb + 5 * 16384, (float*)d_out);
}